// Round 1
// baseline (34.026 us; speedup 1.0000x reference)
//
#include <hip/hip_runtime.h>
#include <math.h>

namespace {

constexpr int NOUT   = 10240;
constexpr int OPB    = 8;      // coarse nodes per block
constexpr int NBATCH = 4;
constexpr int NIJ    = 16;     // so*si receptive field
constexpr int NPD    = 16;     // n_phi * n_dist
constexpr int NC     = 32;     // channels
constexpr int NIN    = NOUT * NIJ;

__device__ __forceinline__ void fma4(float4& a, float s, const float4& v) {
    a.x = fmaf(s, v.x, a.x);
    a.y = fmaf(s, v.y, a.y);
    a.z = fmaf(s, v.z, a.z);
    a.w = fmaf(s, v.w, a.w);
}

__global__ __launch_bounds__(256) void polnorm_kernel(
    const float* __restrict__ x,        // (B, NIN, 1, 1, NC)
    const float* __restrict__ cx,       // (1, NOUT, 4, 4)
    const float* __restrict__ cy,       // (1, NOUT, 4, 4)
    const float* __restrict__ phis,     // (4,)
    const float* __restrict__ dists_p,  // (4,)
    const float* __restrict__ sigma_p,  // (1,)
    float* __restrict__ out)            // (B, NOUT, 1, 4, 4, 1, NC)
{
    __shared__ float s_w[OPB * NPD * NIJ];   // raw weights [o][pd][ij]
    __shared__ float s_inv[OPB * NPD];       // 1/(sum_ij w + 1e-20)

    const int t = threadIdx.x;
    const int o_base = blockIdx.x * OPB;

    // ---------------- fill phase: w + normalization factors ----------------
    {
        const int pd = t >> 4;        // 0..15
        const int ij = t & 15;        // 0..15
        const int p = pd >> 2, d = pd & 3;

        const float dist = 2.0f / (1.0f + expf(-dists_p[d]));  // 2*sigmoid
        const float phi  = phis[p];
        const float mux  = cosf(phi) * dist;
        const float muy  = sinf(phi) * dist;
        float sg = 2.0f / (1.0f + expf(-sigma_p[0]));
        sg = fmaxf(sg, 1e-10f);
        const float coef = -0.5f / (sg * sg);

        #pragma unroll
        for (int k = 0; k < OPB; ++k) {
            const int o = o_base + k;
            const float dx = cx[o * NIJ + ij] - mux;
            const float dy = cy[o * NIJ + ij] - muy;
            const float w = expf(coef * (dx * dx + dy * dy));
            s_w[k * (NPD * NIJ) + t] = w;   // consecutive lanes -> consecutive banks
            // sum over ij = reduction over 16 consecutive lanes
            float s = w;
            s += __shfl_xor(s, 1);
            s += __shfl_xor(s, 2);
            s += __shfl_xor(s, 4);
            s += __shfl_xor(s, 8);
            if (ij == 0) s_inv[k * NPD + pd] = 1.0f / (s + 1e-20f);
        }
    }
    __syncthreads();

    // ---------------- main phase: weighted reduce + store ----------------
    const int o_local = t >> 5;       // 0..7
    const int b       = (t >> 3) & 3; // 0..3
    const int c4      = t & 7;        // float4 lane within 32 channels
    const int o       = o_base + o_local;

    const float4* xp = reinterpret_cast<const float4*>(
        x + ((size_t)b * NIN + (size_t)o * NIJ) * NC) + c4;
    float4 xv[NIJ];
    #pragma unroll
    for (int k = 0; k < NIJ; ++k) xv[k] = xp[(size_t)k * (NC / 4)];

    float4* op = reinterpret_cast<float4*>(
        out + ((size_t)b * NOUT + o) * (size_t)(NPD * NC)) + c4;
    const float* wrow   = s_w + o_local * (NPD * NIJ);
    const float* invrow = s_inv + o_local * NPD;

    #pragma unroll
    for (int q = 0; q < NPD; ++q) {
        const float4 w0 = reinterpret_cast<const float4*>(wrow + q * NIJ)[0];
        const float4 w1 = reinterpret_cast<const float4*>(wrow + q * NIJ)[1];
        const float4 w2 = reinterpret_cast<const float4*>(wrow + q * NIJ)[2];
        const float4 w3 = reinterpret_cast<const float4*>(wrow + q * NIJ)[3];
        float4 acc = make_float4(0.f, 0.f, 0.f, 0.f);
        fma4(acc, w0.x, xv[0]);  fma4(acc, w0.y, xv[1]);
        fma4(acc, w0.z, xv[2]);  fma4(acc, w0.w, xv[3]);
        fma4(acc, w1.x, xv[4]);  fma4(acc, w1.y, xv[5]);
        fma4(acc, w1.z, xv[6]);  fma4(acc, w1.w, xv[7]);
        fma4(acc, w2.x, xv[8]);  fma4(acc, w2.y, xv[9]);
        fma4(acc, w2.z, xv[10]); fma4(acc, w2.w, xv[11]);
        fma4(acc, w3.x, xv[12]); fma4(acc, w3.y, xv[13]);
        fma4(acc, w3.z, xv[14]); fma4(acc, w3.w, xv[15]);
        const float inv = invrow[q];
        acc.x *= inv; acc.y *= inv; acc.z *= inv; acc.w *= inv;
        op[(size_t)q * (NC / 4)] = acc;
    }
}

} // namespace

extern "C" void kernel_launch(void* const* d_in, const int* in_sizes, int n_in,
                              void* d_out, int out_size, void* d_ws, size_t ws_size,
                              hipStream_t stream) {
    const float* x  = (const float*)d_in[0];
    const float* cx = (const float*)d_in[1];
    const float* cy = (const float*)d_in[2];
    const float* ph = (const float*)d_in[3];
    const float* dp = (const float*)d_in[4];
    const float* sp = (const float*)d_in[5];
    float* out = (float*)d_out;

    dim3 grid(NOUT / OPB);
    dim3 block(256);
    hipLaunchKernelGGL(polnorm_kernel, grid, block, 0, stream,
                       x, cx, cy, ph, dp, sp, out);
}